// Round 2
// baseline (226.289 us; speedup 1.0000x reference)
//
#include <hip/hip_runtime.h>

#define NPIX 4194304   // 64*256*256 per image
#define BATCH 4
#define MINK 1024ULL
#define NBINS 4096

typedef unsigned long long u64;

__device__ __forceinline__ float pix_loss(float v0, float v1, float v2, int t) {
    float m = fmaxf(fmaxf(v0, v1), v2);
    float lse = m + __logf(__expf(v0 - m) + __expf(v1 - m) + __expf(v2 - m));
    float xt = (t == 0) ? v0 : ((t == 1) ? v1 : v2);
    return lse - xt;
}

// K1: per-image {fg_sum, bg_sum, fg_cnt}. Straight-line: 8 pixels/thread,
// all 8 vector loads issued before any use (max MLP per wave).
__global__ __launch_bounds__(256) void k_reduce(const float* __restrict__ x,
                                                const int* __restrict__ tg,
                                                double* __restrict__ fg_sum,
                                                double* __restrict__ bg_sum,
                                                u64* __restrict__ fg_cnt) {
    const int b = blockIdx.y;
    const float* xb = x + (size_t)b * 3 * NPIX;
    const int* tb = tg + (size_t)b * NPIX;
    const int i = (blockIdx.x * 256 + threadIdx.x) * 8;

    const float4 a0 = *(const float4*)(xb + i);
    const float4 a1 = *(const float4*)(xb + i + 4);
    const float4 c0 = *(const float4*)(xb + NPIX + i);
    const float4 c1 = *(const float4*)(xb + NPIX + i + 4);
    const float4 d0 = *(const float4*)(xb + 2 * NPIX + i);
    const float4 d1 = *(const float4*)(xb + 2 * NPIX + i + 4);
    const int4 t0 = *(const int4*)(tb + i);
    const int4 t1 = *(const int4*)(tb + i + 4);

    const float va[8] = {a0.x, a0.y, a0.z, a0.w, a1.x, a1.y, a1.z, a1.w};
    const float vc[8] = {c0.x, c0.y, c0.z, c0.w, c1.x, c1.y, c1.z, c1.w};
    const float vd[8] = {d0.x, d0.y, d0.z, d0.w, d1.x, d1.y, d1.z, d1.w};
    const int vt[8] = {t0.x, t0.y, t0.z, t0.w, t1.x, t1.y, t1.z, t1.w};

    float fs = 0.f, bs = 0.f;
    int fc = 0;
#pragma unroll
    for (int j = 0; j < 8; ++j) {
        const float l = pix_loss(va[j], vc[j], vd[j], vt[j]);
        if (vt[j] > 0) { fs += l; fc++; } else { bs += l; }
    }

#pragma unroll
    for (int off = 32; off > 0; off >>= 1) {
        fs += __shfl_down(fs, off);
        bs += __shfl_down(bs, off);
        fc += __shfl_down(fc, off);
    }
    __shared__ float sfs[4], sbs[4];
    __shared__ int sfc[4];
    const int wid = threadIdx.x >> 6;
    if ((threadIdx.x & 63) == 0) { sfs[wid] = fs; sbs[wid] = bs; sfc[wid] = fc; }
    __syncthreads();
    if (threadIdx.x == 0) {
        atomicAdd(&fg_sum[b], (double)(sfs[0] + sfs[1] + sfs[2] + sfs[3]));
        atomicAdd(&bg_sum[b], (double)(sbs[0] + sbs[1] + sbs[2] + sbs[3]));
        atomicAdd(&fg_cnt[b], (u64)(sfc[0] + sfc[1] + sfc[2] + sfc[3]));
    }
}

// K2: histogram of bg losses (float-bit bins, order-preserving for x>=0).
// Early-exits when k == bg_num (the case for this data) -> costs only a launch.
__global__ __launch_bounds__(256) void k_hist(const float* __restrict__ x,
                                              const int* __restrict__ tg,
                                              const u64* __restrict__ fg_cnt,
                                              unsigned int* __restrict__ hist_cnt,
                                              float* __restrict__ hist_sum) {
    const int b = blockIdx.y;
    const u64 fc = fg_cnt[b];
    const u64 bg = (u64)NPIX - fc;
    u64 mk = fc > MINK ? fc : MINK;
    const u64 k = bg < mk ? bg : mk;
    if (k >= bg) return;  // top-k covers all bg: bg_sum suffices, no hist needed

    __shared__ unsigned int hc[NBINS];
    __shared__ float hs[NBINS];
    for (int i = threadIdx.x; i < NBINS; i += blockDim.x) { hc[i] = 0u; hs[i] = 0.f; }
    __syncthreads();

    const float* xb = x + (size_t)b * 3 * NPIX;
    const int* tb = tg + (size_t)b * NPIX;
    const int stride = gridDim.x * blockDim.x * 4;
    for (int i = (blockIdx.x * blockDim.x + threadIdx.x) * 4; i < NPIX; i += stride) {
        const float4 a = *(const float4*)(xb + i);
        const float4 c = *(const float4*)(xb + NPIX + i);
        const float4 d = *(const float4*)(xb + 2 * NPIX + i);
        const int4 t4 = *(const int4*)(tb + i);
        float v[4][3] = {{a.x, c.x, d.x}, {a.y, c.y, d.y}, {a.z, c.z, d.z}, {a.w, c.w, d.w}};
        int tt[4] = {t4.x, t4.y, t4.z, t4.w};
#pragma unroll
        for (int j = 0; j < 4; ++j) {
            if (tt[j] == 0) {
                float l = fmaxf(pix_loss(v[j][0], v[j][1], v[j][2], tt[j]), 0.f);
                unsigned bin = __float_as_uint(l) >> 20;  // 12-bit, monotone for x>=0
                atomicAdd(&hc[bin], 1u);
                atomicAdd(&hs[bin], l);
            }
        }
    }
    __syncthreads();
    for (int i = threadIdx.x; i < NBINS; i += blockDim.x) {
        if (hc[i]) {
            atomicAdd(&hist_cnt[(size_t)b * NBINS + i], hc[i]);
            atomicAdd(&hist_sum[(size_t)b * NBINS + i], hs[i]);
        }
    }
}

// K3: finalize scalar
__global__ void k_final(const double* __restrict__ fg_sum,
                        const double* __restrict__ bg_sum,
                        const u64* __restrict__ fg_cnt,
                        const unsigned int* __restrict__ hist_cnt,
                        const float* __restrict__ hist_sum,
                        int have_hist, float* __restrict__ out) {
    if (threadIdx.x != 0 || blockIdx.x != 0) return;
    double acc = 0.0;
    for (int b = 0; b < BATCH; ++b) {
        const u64 fc = fg_cnt[b];
        const u64 bg = (u64)NPIX - fc;
        u64 mk = fc > MINK ? fc : MINK;
        const u64 k = bg < mk ? bg : mk;
        double fg_term = (fc > 0) ? fg_sum[b] / (double)fc : 0.0;
        double bg_topk;
        if (k >= bg || !have_hist) {
            bg_topk = bg_sum[b];
        } else {
            u64 cnt = 0;
            double s = 0.0;
            bg_topk = 0.0;
            for (int i = NBINS - 1; i >= 0; --i) {
                unsigned c = hist_cnt[(size_t)b * NBINS + i];
                if (cnt + c >= k) {
                    double edge = (double)__uint_as_float(((unsigned)i) << 20);
                    bg_topk = s + (double)(k - cnt) * edge;
                    break;
                }
                cnt += c;
                s += (double)hist_sum[(size_t)b * NBINS + i];
            }
        }
        u64 kd = k > 1 ? k : 1;
        double bg_term = (bg > 0) ? bg_topk / (double)kd : 0.0;
        acc += fg_term + bg_term;
    }
    out[0] = (float)(acc / (double)BATCH);
}

extern "C" void kernel_launch(void* const* d_in, const int* in_sizes, int n_in,
                              void* d_out, int out_size, void* d_ws, size_t ws_size,
                              hipStream_t stream) {
    const float* x = (const float*)d_in[0];
    const int* tg = (const int*)d_in[1];
    float* out = (float*)d_out;

    char* ws = (char*)d_ws;
    double* fg_sum = (double*)ws;                    // 32 B
    double* bg_sum = (double*)(ws + 32);             // 32 B
    u64* fg_cnt = (u64*)(ws + 64);                   // 32 B
    unsigned int* hist_cnt = (unsigned int*)(ws + 128);
    float* hist_sum = (float*)(ws + 128 + (size_t)BATCH * NBINS * 4);
    const size_t need = 128 + (size_t)BATCH * NBINS * 8;
    const int have_hist = (ws_size >= need) ? 1 : 0;

    hipMemsetAsync(d_ws, 0, have_hist ? need : (size_t)128, stream);

    dim3 grid(NPIX / (256 * 8), BATCH), block(256);   // (2048, 4)
    k_reduce<<<grid, block, 0, stream>>>(x, tg, fg_sum, bg_sum, fg_cnt);
    if (have_hist) {
        dim3 hgrid(1024, BATCH);
        k_hist<<<hgrid, block, 0, stream>>>(x, tg, fg_cnt, hist_cnt, hist_sum);
    }
    k_final<<<1, 64, 0, stream>>>(fg_sum, bg_sum, fg_cnt, hist_cnt, hist_sum, have_hist, out);
}

// Round 3
// 61.411 us; speedup vs baseline: 3.6848x; 3.6848x over previous
//
#include <hip/hip_runtime.h>

#define NPIX 4194304   // 64*256*256 per image
#define BATCH 4
#define MINK 1024ULL
#define NBINS 4096
#define G1 1024        // blocks per image in k_reduce

typedef unsigned long long u64;

__device__ __forceinline__ float pix_loss(float v0, float v1, float v2, int t) {
    float m = fmaxf(fmaxf(v0, v1), v2);
    float lse = m + __logf(__expf(v0 - m) + __expf(v1 - m) + __expf(v2 - m));
    float xt = (t == 0) ? v0 : ((t == 1) ? v1 : v2);
    return lse - xt;
}

// K1: per-block partials via PLAIN STORES to unique slots — zero atomics.
__global__ __launch_bounds__(256) void k_reduce(const float* __restrict__ x,
                                                const int* __restrict__ tg,
                                                float* __restrict__ pfs,
                                                float* __restrict__ pbs,
                                                unsigned* __restrict__ pfc) {
    const int b = blockIdx.y;
    const float* xb = x + (size_t)b * 3 * NPIX;
    const int* tb = tg + (size_t)b * NPIX;
    float fs = 0.f, bs = 0.f;
    int fc = 0;
    const int stride = G1 * 256 * 4;  // pixels per grid sweep
#pragma unroll
    for (int it = 0; it < NPIX / stride; ++it) {
        const int i = it * stride + (blockIdx.x * 256 + threadIdx.x) * 4;
        const float4 a = *(const float4*)(xb + i);
        const float4 c = *(const float4*)(xb + NPIX + i);
        const float4 d = *(const float4*)(xb + 2 * NPIX + i);
        const int4 t4 = *(const int4*)(tb + i);
        float l;
        l = pix_loss(a.x, c.x, d.x, t4.x); if (t4.x > 0) { fs += l; fc++; } else bs += l;
        l = pix_loss(a.y, c.y, d.y, t4.y); if (t4.y > 0) { fs += l; fc++; } else bs += l;
        l = pix_loss(a.z, c.z, d.z, t4.z); if (t4.z > 0) { fs += l; fc++; } else bs += l;
        l = pix_loss(a.w, c.w, d.w, t4.w); if (t4.w > 0) { fs += l; fc++; } else bs += l;
    }
#pragma unroll
    for (int off = 32; off > 0; off >>= 1) {
        fs += __shfl_down(fs, off);
        bs += __shfl_down(bs, off);
        fc += __shfl_down(fc, off);
    }
    __shared__ float sfs[4], sbs[4];
    __shared__ int sfc[4];
    const int wid = threadIdx.x >> 6;
    if ((threadIdx.x & 63) == 0) { sfs[wid] = fs; sbs[wid] = bs; sfc[wid] = fc; }
    __syncthreads();
    if (threadIdx.x == 0) {
        const int slot = b * G1 + blockIdx.x;
        pfs[slot] = sfs[0] + sfs[1] + sfs[2] + sfs[3];
        pbs[slot] = sbs[0] + sbs[1] + sbs[2] + sbs[3];
        pfc[slot] = (unsigned)(sfc[0] + sfc[1] + sfc[2] + sfc[3]);
    }
}

// K2: reduce partials -> per-image totals; also zero hist buffers (replaces memset).
__global__ __launch_bounds__(256) void k_sum(const float* __restrict__ pfs,
                                             const float* __restrict__ pbs,
                                             const unsigned* __restrict__ pfc,
                                             double* __restrict__ fg_sum,
                                             double* __restrict__ bg_sum,
                                             u64* __restrict__ fg_cnt,
                                             unsigned* __restrict__ hist_cnt,
                                             float* __restrict__ hist_sum,
                                             int have_hist) {
    __shared__ double sd0[4], sd1[4];
    __shared__ u64 sc[4];
    for (int b = 0; b < BATCH; ++b) {
        double fs = 0.0, bs = 0.0;
        u64 fc = 0;
        for (int i = threadIdx.x; i < G1; i += 256) {
            fs += (double)pfs[b * G1 + i];
            bs += (double)pbs[b * G1 + i];
            fc += (u64)pfc[b * G1 + i];
        }
#pragma unroll
        for (int off = 32; off > 0; off >>= 1) {
            fs += __shfl_down(fs, off);
            bs += __shfl_down(bs, off);
            fc += __shfl_down(fc, off);
        }
        const int wid = threadIdx.x >> 6;
        if ((threadIdx.x & 63) == 0) { sd0[wid] = fs; sd1[wid] = bs; sc[wid] = fc; }
        __syncthreads();
        if (threadIdx.x == 0) {
            fg_sum[b] = sd0[0] + sd0[1] + sd0[2] + sd0[3];
            bg_sum[b] = sd1[0] + sd1[1] + sd1[2] + sd1[3];
            fg_cnt[b] = sc[0] + sc[1] + sc[2] + sc[3];
        }
        __syncthreads();
    }
    if (have_hist) {
        for (int i = threadIdx.x; i < BATCH * NBINS; i += 256) {
            hist_cnt[i] = 0u;
            hist_sum[i] = 0.f;
        }
    }
}

// K3: histogram of bg losses — early-exits when k == bg_num (this data).
__global__ __launch_bounds__(256) void k_hist(const float* __restrict__ x,
                                              const int* __restrict__ tg,
                                              const u64* __restrict__ fg_cnt,
                                              unsigned int* __restrict__ hist_cnt,
                                              float* __restrict__ hist_sum) {
    const int b = blockIdx.y;
    const u64 fc = fg_cnt[b];
    const u64 bg = (u64)NPIX - fc;
    u64 mk = fc > MINK ? fc : MINK;
    const u64 k = bg < mk ? bg : mk;
    if (k >= bg) return;  // top-k covers all bg: bg_sum suffices

    __shared__ unsigned int hc[NBINS];
    __shared__ float hs[NBINS];
    for (int i = threadIdx.x; i < NBINS; i += blockDim.x) { hc[i] = 0u; hs[i] = 0.f; }
    __syncthreads();

    const float* xb = x + (size_t)b * 3 * NPIX;
    const int* tb = tg + (size_t)b * NPIX;
    const int stride = gridDim.x * blockDim.x * 4;
    for (int i = (blockIdx.x * blockDim.x + threadIdx.x) * 4; i < NPIX; i += stride) {
        const float4 a = *(const float4*)(xb + i);
        const float4 c = *(const float4*)(xb + NPIX + i);
        const float4 d = *(const float4*)(xb + 2 * NPIX + i);
        const int4 t4 = *(const int4*)(tb + i);
        float v[4][3] = {{a.x, c.x, d.x}, {a.y, c.y, d.y}, {a.z, c.z, d.z}, {a.w, c.w, d.w}};
        int tt[4] = {t4.x, t4.y, t4.z, t4.w};
#pragma unroll
        for (int j = 0; j < 4; ++j) {
            if (tt[j] == 0) {
                float l = fmaxf(pix_loss(v[j][0], v[j][1], v[j][2], tt[j]), 0.f);
                unsigned bin = __float_as_uint(l) >> 20;  // monotone for x>=0
                atomicAdd(&hc[bin], 1u);
                atomicAdd(&hs[bin], l);
            }
        }
    }
    __syncthreads();
    for (int i = threadIdx.x; i < NBINS; i += blockDim.x) {
        if (hc[i]) {
            atomicAdd(&hist_cnt[(size_t)b * NBINS + i], hc[i]);
            atomicAdd(&hist_sum[(size_t)b * NBINS + i], hs[i]);
        }
    }
}

// K4: finalize scalar
__global__ void k_final(const double* __restrict__ fg_sum,
                        const double* __restrict__ bg_sum,
                        const u64* __restrict__ fg_cnt,
                        const unsigned int* __restrict__ hist_cnt,
                        const float* __restrict__ hist_sum,
                        int have_hist, float* __restrict__ out) {
    if (threadIdx.x != 0 || blockIdx.x != 0) return;
    double acc = 0.0;
    for (int b = 0; b < BATCH; ++b) {
        const u64 fc = fg_cnt[b];
        const u64 bg = (u64)NPIX - fc;
        u64 mk = fc > MINK ? fc : MINK;
        const u64 k = bg < mk ? bg : mk;
        double fg_term = (fc > 0) ? fg_sum[b] / (double)fc : 0.0;
        double bg_topk;
        if (k >= bg || !have_hist) {
            bg_topk = bg_sum[b];
        } else {
            u64 cnt = 0;
            double s = 0.0;
            bg_topk = 0.0;
            for (int i = NBINS - 1; i >= 0; --i) {
                unsigned c = hist_cnt[(size_t)b * NBINS + i];
                if (cnt + c >= k) {
                    double edge = (double)__uint_as_float(((unsigned)i) << 20);
                    bg_topk = s + (double)(k - cnt) * edge;
                    break;
                }
                cnt += c;
                s += (double)hist_sum[(size_t)b * NBINS + i];
            }
        }
        u64 kd = k > 1 ? k : 1;
        double bg_term = (bg > 0) ? bg_topk / (double)kd : 0.0;
        acc += fg_term + bg_term;
    }
    out[0] = (float)(acc / (double)BATCH);
}

extern "C" void kernel_launch(void* const* d_in, const int* in_sizes, int n_in,
                              void* d_out, int out_size, void* d_ws, size_t ws_size,
                              hipStream_t stream) {
    const float* x = (const float*)d_in[0];
    const int* tg = (const int*)d_in[1];
    float* out = (float*)d_out;

    char* ws = (char*)d_ws;
    float* pfs = (float*)ws;                                   // 16 KB
    float* pbs = (float*)(ws + 16384);                         // 16 KB
    unsigned* pfc = (unsigned*)(ws + 32768);                   // 16 KB
    double* fg_sum = (double*)(ws + 49152);                    // 32 B
    double* bg_sum = (double*)(ws + 49184);                    // 32 B
    u64* fg_cnt = (u64*)(ws + 49216);                          // 32 B
    unsigned* hist_cnt = (unsigned*)(ws + 49280);              // 64 KB
    float* hist_sum = (float*)(ws + 49280 + (size_t)BATCH * NBINS * 4);  // 64 KB
    const size_t need = 49280 + (size_t)BATCH * NBINS * 8;
    const int have_hist = (ws_size >= need) ? 1 : 0;

    dim3 block(256);
    dim3 grid1(G1, BATCH);
    k_reduce<<<grid1, block, 0, stream>>>(x, tg, pfs, pbs, pfc);
    k_sum<<<1, block, 0, stream>>>(pfs, pbs, pfc, fg_sum, bg_sum, fg_cnt,
                                   hist_cnt, hist_sum, have_hist);
    if (have_hist) {
        dim3 hgrid(1024, BATCH);
        k_hist<<<hgrid, block, 0, stream>>>(x, tg, fg_cnt, hist_cnt, hist_sum);
    }
    k_final<<<1, 64, 0, stream>>>(fg_sum, bg_sum, fg_cnt, hist_cnt, hist_sum, have_hist, out);
}

// Round 4
// 58.073 us; speedup vs baseline: 3.8967x; 1.0575x over previous
//
#include <hip/hip_runtime.h>

#define NPIX 4194304   // 64*256*256 per image
#define BATCH 4
#define MINK 1024ULL
#define NBINS 4096
#define G1 1024        // blocks per image in k_reduce
#define HG 256         // blocks per image in k_hist

typedef unsigned long long u64;

__device__ __forceinline__ float pix_loss(float v0, float v1, float v2, int t) {
    float m = fmaxf(fmaxf(v0, v1), v2);
    float lse = m + __logf(__expf(v0 - m) + __expf(v1 - m) + __expf(v2 - m));
    float xt = (t == 0) ? v0 : ((t == 1) ? v1 : v2);
    return lse - xt;
}

// K1: per-block partials via PLAIN STORES to unique slots — zero atomics.
// (unchanged from round 3 — measured ~48 us)
__global__ __launch_bounds__(256) void k_reduce(const float* __restrict__ x,
                                                const int* __restrict__ tg,
                                                float* __restrict__ pfs,
                                                float* __restrict__ pbs,
                                                unsigned* __restrict__ pfc) {
    const int b = blockIdx.y;
    const float* xb = x + (size_t)b * 3 * NPIX;
    const int* tb = tg + (size_t)b * NPIX;
    float fs = 0.f, bs = 0.f;
    int fc = 0;
    const int stride = G1 * 256 * 4;  // pixels per grid sweep
#pragma unroll
    for (int it = 0; it < NPIX / stride; ++it) {
        const int i = it * stride + (blockIdx.x * 256 + threadIdx.x) * 4;
        const float4 a = *(const float4*)(xb + i);
        const float4 c = *(const float4*)(xb + NPIX + i);
        const float4 d = *(const float4*)(xb + 2 * NPIX + i);
        const int4 t4 = *(const int4*)(tb + i);
        float l;
        l = pix_loss(a.x, c.x, d.x, t4.x); if (t4.x > 0) { fs += l; fc++; } else bs += l;
        l = pix_loss(a.y, c.y, d.y, t4.y); if (t4.y > 0) { fs += l; fc++; } else bs += l;
        l = pix_loss(a.z, c.z, d.z, t4.z); if (t4.z > 0) { fs += l; fc++; } else bs += l;
        l = pix_loss(a.w, c.w, d.w, t4.w); if (t4.w > 0) { fs += l; fc++; } else bs += l;
    }
#pragma unroll
    for (int off = 32; off > 0; off >>= 1) {
        fs += __shfl_down(fs, off);
        bs += __shfl_down(bs, off);
        fc += __shfl_down(fc, off);
    }
    __shared__ float sfs[4], sbs[4];
    __shared__ int sfc[4];
    const int wid = threadIdx.x >> 6;
    if ((threadIdx.x & 63) == 0) { sfs[wid] = fs; sbs[wid] = bs; sfc[wid] = fc; }
    __syncthreads();
    if (threadIdx.x == 0) {
        const int slot = b * G1 + blockIdx.x;
        pfs[slot] = sfs[0] + sfs[1] + sfs[2] + sfs[3];
        pbs[slot] = sbs[0] + sbs[1] + sbs[2] + sbs[3];
        pfc[slot] = (unsigned)(sfc[0] + sfc[1] + sfc[2] + sfc[3]);
    }
}

// K2: reduce partials -> totals, WRITE FINAL OUT (valid when k==bg for all
// images), flag images that actually need the top-k path, zero hist + done.
__global__ __launch_bounds__(256) void k_sumfin(const float* __restrict__ pfs,
                                                const float* __restrict__ pbs,
                                                const unsigned* __restrict__ pfc,
                                                double* __restrict__ fg_sum,
                                                double* __restrict__ bg_sum,
                                                u64* __restrict__ fg_cnt,
                                                unsigned* __restrict__ hist_cnt,
                                                float* __restrict__ hist_sum,
                                                unsigned* __restrict__ flags,
                                                float* __restrict__ out,
                                                int have_hist) {
    __shared__ double sd0[4], sd1[4];
    __shared__ u64 sc[4];
    __shared__ double tfs[BATCH], tbs[BATCH];
    __shared__ u64 tfc[BATCH];
    for (int b = 0; b < BATCH; ++b) {
        double fs = 0.0, bs = 0.0;
        u64 fc = 0;
        for (int i = threadIdx.x; i < G1; i += 256) {
            fs += (double)pfs[b * G1 + i];
            bs += (double)pbs[b * G1 + i];
            fc += (u64)pfc[b * G1 + i];
        }
#pragma unroll
        for (int off = 32; off > 0; off >>= 1) {
            fs += __shfl_down(fs, off);
            bs += __shfl_down(bs, off);
            fc += __shfl_down(fc, off);
        }
        const int wid = threadIdx.x >> 6;
        if ((threadIdx.x & 63) == 0) { sd0[wid] = fs; sd1[wid] = bs; sc[wid] = fc; }
        __syncthreads();
        if (threadIdx.x == 0) {
            tfs[b] = sd0[0] + sd0[1] + sd0[2] + sd0[3];
            tbs[b] = sd1[0] + sd1[1] + sd1[2] + sd1[3];
            tfc[b] = sc[0] + sc[1] + sc[2] + sc[3];
            fg_sum[b] = tfs[b];
            bg_sum[b] = tbs[b];
            fg_cnt[b] = tfc[b];
        }
        __syncthreads();
    }
    if (threadIdx.x == 0) {
        double acc = 0.0;
        unsigned need = 0u;
        for (int b = 0; b < BATCH; ++b) {
            const u64 fc = tfc[b];
            const u64 bg = (u64)NPIX - fc;
            u64 mk = fc > MINK ? fc : MINK;
            const u64 k = bg < mk ? bg : mk;
            double fg_term = (fc > 0) ? tfs[b] / (double)fc : 0.0;
            u64 kd = k > 1 ? k : 1;
            double bg_term = (bg > 0) ? tbs[b] / (double)kd : 0.0;  // valid iff k>=bg
            if (k < bg && have_hist) need |= (1u << b);
            acc += fg_term + bg_term;
        }
        out[0] = (float)(acc / (double)BATCH);
        flags[0] = need;   // need_mask
        flags[1] = 0u;     // done counter for k_hist
    }
    if (have_hist) {
        uint4 z4 = make_uint4(0u, 0u, 0u, 0u);
        uint4* hc4 = (uint4*)hist_cnt;
        uint4* hs4 = (uint4*)hist_sum;
        for (int i = threadIdx.x; i < BATCH * NBINS / 4; i += 256) {
            hc4[i] = z4;
            hs4[i] = z4;
        }
    }
}

// K3: histogram + last-block fixup. On data where no image needs top-k
// (need_mask==0) every block returns immediately.
__global__ __launch_bounds__(256) void k_hist(const float* __restrict__ x,
                                              const int* __restrict__ tg,
                                              const double* __restrict__ fg_sum,
                                              const double* __restrict__ bg_sum,
                                              const u64* __restrict__ fg_cnt,
                                              unsigned* __restrict__ hist_cnt,
                                              float* __restrict__ hist_sum,
                                              unsigned* __restrict__ flags,
                                              float* __restrict__ out) {
    const unsigned need = flags[0];
    if (need == 0u) return;

    const int b = blockIdx.y;
    __shared__ unsigned hc[NBINS];
    __shared__ float hs[NBINS];

    if (need & (1u << b)) {
        for (int i = threadIdx.x; i < NBINS; i += 256) { hc[i] = 0u; hs[i] = 0.f; }
        __syncthreads();
        const float* xb = x + (size_t)b * 3 * NPIX;
        const int* tb = tg + (size_t)b * NPIX;
        const int stride = HG * 256 * 4;
        for (int i = (blockIdx.x * 256 + threadIdx.x) * 4; i < NPIX; i += stride) {
            const float4 a = *(const float4*)(xb + i);
            const float4 c = *(const float4*)(xb + NPIX + i);
            const float4 d = *(const float4*)(xb + 2 * NPIX + i);
            const int4 t4 = *(const int4*)(tb + i);
            float v[4][3] = {{a.x, c.x, d.x}, {a.y, c.y, d.y}, {a.z, c.z, d.z}, {a.w, c.w, d.w}};
            int tt[4] = {t4.x, t4.y, t4.z, t4.w};
#pragma unroll
            for (int j = 0; j < 4; ++j) {
                if (tt[j] == 0) {
                    float l = fmaxf(pix_loss(v[j][0], v[j][1], v[j][2], tt[j]), 0.f);
                    unsigned bin = __float_as_uint(l) >> 20;  // monotone for x>=0
                    atomicAdd(&hc[bin], 1u);
                    atomicAdd(&hs[bin], l);
                }
            }
        }
        __syncthreads();
        for (int i = threadIdx.x; i < NBINS; i += 256) {
            if (hc[i]) {
                atomicAdd(&hist_cnt[(size_t)b * NBINS + i], hc[i]);
                atomicAdd(&hist_sum[(size_t)b * NBINS + i], hs[i]);
            }
        }
    }

    // done protocol: last of the HG*BATCH blocks performs the fixup.
    __threadfence();
    __syncthreads();
    __shared__ int is_last;
    if (threadIdx.x == 0) {
        unsigned v = atomicAdd(&flags[1], 1u);
        is_last = (v == (unsigned)(HG * BATCH) - 1u) ? 1 : 0;
    }
    __syncthreads();
    if (!is_last) return;

    __threadfence();
    __shared__ double sbt[BATCH];
    for (int b2 = 0; b2 < BATCH; ++b2) {
        if (need & (1u << b2)) {
            // stage this image's global hist into LDS (coherent loads)
            for (int i = threadIdx.x; i < NBINS; i += 256) {
                hc[i] = __hip_atomic_load(&hist_cnt[(size_t)b2 * NBINS + i],
                                          __ATOMIC_ACQUIRE, __HIP_MEMORY_SCOPE_AGENT);
                hs[i] = __hip_atomic_load(&hist_sum[(size_t)b2 * NBINS + i],
                                          __ATOMIC_ACQUIRE, __HIP_MEMORY_SCOPE_AGENT);
            }
            __syncthreads();
            if (threadIdx.x == 0) {
                const u64 fc = fg_cnt[b2];
                const u64 bg = (u64)NPIX - fc;
                u64 mk = fc > MINK ? fc : MINK;
                const u64 k = bg < mk ? bg : mk;
                u64 cnt = 0;
                double s = 0.0, bg_topk = 0.0;
                for (int i = NBINS - 1; i >= 0; --i) {
                    unsigned c = hc[i];
                    if (cnt + c >= k) {
                        double edge = (double)__uint_as_float(((unsigned)i) << 20);
                        bg_topk = s + (double)(k - cnt) * edge;
                        break;
                    }
                    cnt += c;
                    s += (double)hs[i];
                }
                sbt[b2] = bg_topk;
            }
            __syncthreads();
        }
    }
    if (threadIdx.x == 0) {
        double acc = 0.0;
        for (int b2 = 0; b2 < BATCH; ++b2) {
            const u64 fc = fg_cnt[b2];
            const u64 bg = (u64)NPIX - fc;
            u64 mk = fc > MINK ? fc : MINK;
            const u64 k = bg < mk ? bg : mk;
            double fg_term = (fc > 0) ? fg_sum[b2] / (double)fc : 0.0;
            double bg_topk = (need & (1u << b2)) ? sbt[b2] : bg_sum[b2];
            u64 kd = k > 1 ? k : 1;
            double bg_term = (bg > 0) ? bg_topk / (double)kd : 0.0;
            acc += fg_term + bg_term;
        }
        out[0] = (float)(acc / (double)BATCH);
    }
}

extern "C" void kernel_launch(void* const* d_in, const int* in_sizes, int n_in,
                              void* d_out, int out_size, void* d_ws, size_t ws_size,
                              hipStream_t stream) {
    const float* x = (const float*)d_in[0];
    const int* tg = (const int*)d_in[1];
    float* out = (float*)d_out;

    char* ws = (char*)d_ws;
    float* pfs = (float*)ws;                                   // 16 KB
    float* pbs = (float*)(ws + 16384);                         // 16 KB
    unsigned* pfc = (unsigned*)(ws + 32768);                   // 16 KB
    double* fg_sum = (double*)(ws + 49152);                    // 32 B
    double* bg_sum = (double*)(ws + 49184);                    // 32 B
    u64* fg_cnt = (u64*)(ws + 49216);                          // 32 B
    unsigned* flags = (unsigned*)(ws + 49248);                 // 32 B
    unsigned* hist_cnt = (unsigned*)(ws + 49280);              // 64 KB
    float* hist_sum = (float*)(ws + 49280 + (size_t)BATCH * NBINS * 4);  // 64 KB
    const size_t need_ws = 49280 + (size_t)BATCH * NBINS * 8;
    const int have_hist = (ws_size >= need_ws) ? 1 : 0;

    dim3 block(256);
    dim3 grid1(G1, BATCH);
    k_reduce<<<grid1, block, 0, stream>>>(x, tg, pfs, pbs, pfc);
    k_sumfin<<<1, block, 0, stream>>>(pfs, pbs, pfc, fg_sum, bg_sum, fg_cnt,
                                      hist_cnt, hist_sum, flags, out, have_hist);
    if (have_hist) {
        dim3 hgrid(HG, BATCH);
        k_hist<<<hgrid, block, 0, stream>>>(x, tg, fg_sum, bg_sum, fg_cnt,
                                            hist_cnt, hist_sum, flags, out);
    }
}

// Round 6
// 55.294 us; speedup vs baseline: 4.0925x; 1.0503x over previous
//
#include <hip/hip_runtime.h>

#define NPIX 4194304   // 64*256*256 per image
#define BATCH 4
#define MINK 1024ULL
#define NBINS 4096
#define G1 1024        // blocks per image in k_reduce
#define HG 256         // blocks per image in k_hist

typedef unsigned long long u64;
typedef int vint4 __attribute__((ext_vector_type(4)));   // native vector: OK for nontemporal builtin

__device__ __forceinline__ float pix_loss(float v0, float v1, float v2, int t) {
    float m = fmaxf(fmaxf(v0, v1), v2);
    float lse = m + __logf(__expf(v0 - m) + __expf(v1 - m) + __expf(v2 - m));
    float xt = (t == 0) ? v0 : ((t == 1) ? v1 : v2);
    return lse - xt;
}

// K1: per-block partials via PLAIN STORES to unique slots — zero atomics.
// Target stream is loaded NON-TEMPORAL (nt, no LLC allocate): the 201 MB of
// input planes then fit the 256 MiB L3 and stay resident across replays,
// replacing ~50% LRU thrash with a deterministic partition.
__global__ __launch_bounds__(256) void k_reduce(const float* __restrict__ x,
                                                const int* __restrict__ tg,
                                                float* __restrict__ pfs,
                                                float* __restrict__ pbs,
                                                unsigned* __restrict__ pfc) {
    const int b = blockIdx.y;
    const float* xb = x + (size_t)b * 3 * NPIX;
    const int* tb = tg + (size_t)b * NPIX;
    float fs = 0.f, bs = 0.f;
    int fc = 0;
    const int stride = G1 * 256 * 4;  // pixels per grid sweep
#pragma unroll
    for (int it = 0; it < NPIX / stride; ++it) {
        const int i = it * stride + (blockIdx.x * 256 + threadIdx.x) * 4;
        const float4 a = *(const float4*)(xb + i);
        const float4 c = *(const float4*)(xb + NPIX + i);
        const float4 d = *(const float4*)(xb + 2 * NPIX + i);
        const vint4 t4 = __builtin_nontemporal_load((const vint4*)(tb + i));
        float l;
        l = pix_loss(a.x, c.x, d.x, t4[0]); if (t4[0] > 0) { fs += l; fc++; } else bs += l;
        l = pix_loss(a.y, c.y, d.y, t4[1]); if (t4[1] > 0) { fs += l; fc++; } else bs += l;
        l = pix_loss(a.z, c.z, d.z, t4[2]); if (t4[2] > 0) { fs += l; fc++; } else bs += l;
        l = pix_loss(a.w, c.w, d.w, t4[3]); if (t4[3] > 0) { fs += l; fc++; } else bs += l;
    }
#pragma unroll
    for (int off = 32; off > 0; off >>= 1) {
        fs += __shfl_down(fs, off);
        bs += __shfl_down(bs, off);
        fc += __shfl_down(fc, off);
    }
    __shared__ float sfs[4], sbs[4];
    __shared__ int sfc[4];
    const int wid = threadIdx.x >> 6;
    if ((threadIdx.x & 63) == 0) { sfs[wid] = fs; sbs[wid] = bs; sfc[wid] = fc; }
    __syncthreads();
    if (threadIdx.x == 0) {
        const int slot = b * G1 + blockIdx.x;
        pfs[slot] = sfs[0] + sfs[1] + sfs[2] + sfs[3];
        pbs[slot] = sbs[0] + sbs[1] + sbs[2] + sbs[3];
        pfc[slot] = (unsigned)(sfc[0] + sfc[1] + sfc[2] + sfc[3]);
    }
}

// K2: reduce partials -> totals, WRITE FINAL OUT (valid when k==bg for all
// images), flag images that actually need the top-k path, zero hist + done.
__global__ __launch_bounds__(256) void k_sumfin(const float* __restrict__ pfs,
                                                const float* __restrict__ pbs,
                                                const unsigned* __restrict__ pfc,
                                                double* __restrict__ fg_sum,
                                                double* __restrict__ bg_sum,
                                                u64* __restrict__ fg_cnt,
                                                unsigned* __restrict__ hist_cnt,
                                                float* __restrict__ hist_sum,
                                                unsigned* __restrict__ flags,
                                                float* __restrict__ out,
                                                int have_hist) {
    __shared__ double sd0[4], sd1[4];
    __shared__ u64 sc[4];
    __shared__ double tfs[BATCH], tbs[BATCH];
    __shared__ u64 tfc[BATCH];
    const float4* pfs4 = (const float4*)pfs;
    const float4* pbs4 = (const float4*)pbs;
    const uint4* pfc4 = (const uint4*)pfc;
    for (int b = 0; b < BATCH; ++b) {
        // G1/4 = 256 float4 slots per image: exactly one vector load per thread
        const float4 f4 = pfs4[b * (G1 / 4) + threadIdx.x];
        const float4 b4 = pbs4[b * (G1 / 4) + threadIdx.x];
        const uint4 c4 = pfc4[b * (G1 / 4) + threadIdx.x];
        double fs = (double)f4.x + (double)f4.y + (double)f4.z + (double)f4.w;
        double bs = (double)b4.x + (double)b4.y + (double)b4.z + (double)b4.w;
        u64 fc = (u64)c4.x + c4.y + c4.z + c4.w;
#pragma unroll
        for (int off = 32; off > 0; off >>= 1) {
            fs += __shfl_down(fs, off);
            bs += __shfl_down(bs, off);
            fc += __shfl_down(fc, off);
        }
        const int wid = threadIdx.x >> 6;
        if ((threadIdx.x & 63) == 0) { sd0[wid] = fs; sd1[wid] = bs; sc[wid] = fc; }
        __syncthreads();
        if (threadIdx.x == 0) {
            tfs[b] = sd0[0] + sd0[1] + sd0[2] + sd0[3];
            tbs[b] = sd1[0] + sd1[1] + sd1[2] + sd1[3];
            tfc[b] = sc[0] + sc[1] + sc[2] + sc[3];
            fg_sum[b] = tfs[b];
            bg_sum[b] = tbs[b];
            fg_cnt[b] = tfc[b];
        }
        __syncthreads();
    }
    if (threadIdx.x == 0) {
        double acc = 0.0;
        unsigned need = 0u;
        for (int b = 0; b < BATCH; ++b) {
            const u64 fc = tfc[b];
            const u64 bg = (u64)NPIX - fc;
            u64 mk = fc > MINK ? fc : MINK;
            const u64 k = bg < mk ? bg : mk;
            double fg_term = (fc > 0) ? tfs[b] / (double)fc : 0.0;
            u64 kd = k > 1 ? k : 1;
            double bg_term = (bg > 0) ? tbs[b] / (double)kd : 0.0;  // valid iff k>=bg
            if (k < bg && have_hist) need |= (1u << b);
            acc += fg_term + bg_term;
        }
        out[0] = (float)(acc / (double)BATCH);
        flags[0] = need;   // need_mask
        flags[1] = 0u;     // done counter for k_hist
    }
    if (have_hist) {
        uint4 z4 = make_uint4(0u, 0u, 0u, 0u);
        uint4* hc4 = (uint4*)hist_cnt;
        uint4* hs4 = (uint4*)hist_sum;
        for (int i = threadIdx.x; i < BATCH * NBINS / 4; i += 256) {
            hc4[i] = z4;
            hs4[i] = z4;
        }
    }
}

// K3: histogram + last-block fixup. On data where no image needs top-k
// (need_mask==0) every block returns immediately.
__global__ __launch_bounds__(256) void k_hist(const float* __restrict__ x,
                                              const int* __restrict__ tg,
                                              const double* __restrict__ fg_sum,
                                              const double* __restrict__ bg_sum,
                                              const u64* __restrict__ fg_cnt,
                                              unsigned* __restrict__ hist_cnt,
                                              float* __restrict__ hist_sum,
                                              unsigned* __restrict__ flags,
                                              float* __restrict__ out) {
    const unsigned need = flags[0];
    if (need == 0u) return;

    const int b = blockIdx.y;
    __shared__ unsigned hc[NBINS];
    __shared__ float hs[NBINS];

    if (need & (1u << b)) {
        for (int i = threadIdx.x; i < NBINS; i += 256) { hc[i] = 0u; hs[i] = 0.f; }
        __syncthreads();
        const float* xb = x + (size_t)b * 3 * NPIX;
        const int* tb = tg + (size_t)b * NPIX;
        const int stride = HG * 256 * 4;
        for (int i = (blockIdx.x * 256 + threadIdx.x) * 4; i < NPIX; i += stride) {
            const float4 a = *(const float4*)(xb + i);
            const float4 c = *(const float4*)(xb + NPIX + i);
            const float4 d = *(const float4*)(xb + 2 * NPIX + i);
            const int4 t4 = *(const int4*)(tb + i);
            float v[4][3] = {{a.x, c.x, d.x}, {a.y, c.y, d.y}, {a.z, c.z, d.z}, {a.w, c.w, d.w}};
            int tt[4] = {t4.x, t4.y, t4.z, t4.w};
#pragma unroll
            for (int j = 0; j < 4; ++j) {
                if (tt[j] == 0) {
                    float l = fmaxf(pix_loss(v[j][0], v[j][1], v[j][2], tt[j]), 0.f);
                    unsigned bin = __float_as_uint(l) >> 20;  // monotone for x>=0
                    atomicAdd(&hc[bin], 1u);
                    atomicAdd(&hs[bin], l);
                }
            }
        }
        __syncthreads();
        for (int i = threadIdx.x; i < NBINS; i += 256) {
            if (hc[i]) {
                atomicAdd(&hist_cnt[(size_t)b * NBINS + i], hc[i]);
                atomicAdd(&hist_sum[(size_t)b * NBINS + i], hs[i]);
            }
        }
    }

    // done protocol: last of the HG*BATCH blocks performs the fixup.
    __threadfence();
    __syncthreads();
    __shared__ int is_last;
    if (threadIdx.x == 0) {
        unsigned v = atomicAdd(&flags[1], 1u);
        is_last = (v == (unsigned)(HG * BATCH) - 1u) ? 1 : 0;
    }
    __syncthreads();
    if (!is_last) return;

    __threadfence();
    __shared__ double sbt[BATCH];
    for (int b2 = 0; b2 < BATCH; ++b2) {
        if (need & (1u << b2)) {
            for (int i = threadIdx.x; i < NBINS; i += 256) {
                hc[i] = __hip_atomic_load(&hist_cnt[(size_t)b2 * NBINS + i],
                                          __ATOMIC_ACQUIRE, __HIP_MEMORY_SCOPE_AGENT);
                hs[i] = __hip_atomic_load(&hist_sum[(size_t)b2 * NBINS + i],
                                          __ATOMIC_ACQUIRE, __HIP_MEMORY_SCOPE_AGENT);
            }
            __syncthreads();
            if (threadIdx.x == 0) {
                const u64 fc = fg_cnt[b2];
                const u64 bg = (u64)NPIX - fc;
                u64 mk = fc > MINK ? fc : MINK;
                const u64 k = bg < mk ? bg : mk;
                u64 cnt = 0;
                double s = 0.0, bg_topk = 0.0;
                for (int i = NBINS - 1; i >= 0; --i) {
                    unsigned c = hc[i];
                    if (cnt + c >= k) {
                        double edge = (double)__uint_as_float(((unsigned)i) << 20);
                        bg_topk = s + (double)(k - cnt) * edge;
                        break;
                    }
                    cnt += c;
                    s += (double)hs[i];
                }
                sbt[b2] = bg_topk;
            }
            __syncthreads();
        }
    }
    if (threadIdx.x == 0) {
        double acc = 0.0;
        for (int b2 = 0; b2 < BATCH; ++b2) {
            const u64 fc = fg_cnt[b2];
            const u64 bg = (u64)NPIX - fc;
            u64 mk = fc > MINK ? fc : MINK;
            const u64 k = bg < mk ? bg : mk;
            double fg_term = (fc > 0) ? fg_sum[b2] / (double)fc : 0.0;
            double bg_topk = (need & (1u << b2)) ? sbt[b2] : bg_sum[b2];
            u64 kd = k > 1 ? k : 1;
            double bg_term = (bg > 0) ? bg_topk / (double)kd : 0.0;
            acc += fg_term + bg_term;
        }
        out[0] = (float)(acc / (double)BATCH);
    }
}

extern "C" void kernel_launch(void* const* d_in, const int* in_sizes, int n_in,
                              void* d_out, int out_size, void* d_ws, size_t ws_size,
                              hipStream_t stream) {
    const float* x = (const float*)d_in[0];
    const int* tg = (const int*)d_in[1];
    float* out = (float*)d_out;

    char* ws = (char*)d_ws;
    float* pfs = (float*)ws;                                   // 16 KB
    float* pbs = (float*)(ws + 16384);                         // 16 KB
    unsigned* pfc = (unsigned*)(ws + 32768);                   // 16 KB
    double* fg_sum = (double*)(ws + 49152);                    // 32 B
    double* bg_sum = (double*)(ws + 49184);                    // 32 B
    u64* fg_cnt = (u64*)(ws + 49216);                          // 32 B
    unsigned* flags = (unsigned*)(ws + 49248);                 // 32 B
    unsigned* hist_cnt = (unsigned*)(ws + 49280);              // 64 KB
    float* hist_sum = (float*)(ws + 49280 + (size_t)BATCH * NBINS * 4);  // 64 KB
    const size_t need_ws = 49280 + (size_t)BATCH * NBINS * 8;
    const int have_hist = (ws_size >= need_ws) ? 1 : 0;

    dim3 block(256);
    dim3 grid1(G1, BATCH);
    k_reduce<<<grid1, block, 0, stream>>>(x, tg, pfs, pbs, pfc);
    k_sumfin<<<1, block, 0, stream>>>(pfs, pbs, pfc, fg_sum, bg_sum, fg_cnt,
                                      hist_cnt, hist_sum, flags, out, have_hist);
    if (have_hist) {
        dim3 hgrid(HG, BATCH);
        k_hist<<<hgrid, block, 0, stream>>>(x, tg, fg_sum, bg_sum, fg_cnt,
                                            hist_cnt, hist_sum, flags, out);
    }
}

// Round 7
// 52.132 us; speedup vs baseline: 4.3407x; 1.0607x over previous
//
#include <hip/hip_runtime.h>

#define NPIX 4194304   // 64*256*256 per image
#define BATCH 4
#define MINK 1024ULL
#define NBINS 4096
#define G1 1024        // blocks per image in k_reduce
#define HG 256         // blocks per image in k_tail

typedef unsigned long long u64;
typedef int vint4 __attribute__((ext_vector_type(4)));   // native vector for nontemporal builtin

__device__ __forceinline__ float pix_loss(float v0, float v1, float v2, int t) {
    float m = fmaxf(fmaxf(v0, v1), v2);
    float lse = m + __logf(__expf(v0 - m) + __expf(v1 - m) + __expf(v2 - m));
    float xt = (t == 0) ? v0 : ((t == 1) ? v1 : v2);
    return lse - xt;
}

// K1: per-block partials via PLAIN STORES to unique slots — zero atomics.
// Prologue: image-0 blocks 0..31 zero the 128 KB hist region + flags[1]
// (visible to k_tail via the kernel boundary) — replaces any memset dispatch.
__global__ __launch_bounds__(256) void k_reduce(const float* __restrict__ x,
                                                const int* __restrict__ tg,
                                                float* __restrict__ pfs,
                                                float* __restrict__ pbs,
                                                unsigned* __restrict__ pfc,
                                                uint4* __restrict__ histz,
                                                unsigned* __restrict__ flags,
                                                int have_hist) {
    const int b = blockIdx.y;
    if (b == 0 && blockIdx.x < 32) {
        if (have_hist) histz[blockIdx.x * 256 + threadIdx.x] = make_uint4(0u, 0u, 0u, 0u);
        if (blockIdx.x == 0 && threadIdx.x == 0) flags[1] = 0u;
    }
    const float* xb = x + (size_t)b * 3 * NPIX;
    const int* tb = tg + (size_t)b * NPIX;
    float fs = 0.f, bs = 0.f;
    int fc = 0;
    const int stride = G1 * 256 * 4;  // pixels per grid sweep
#pragma unroll
    for (int it = 0; it < NPIX / stride; ++it) {
        const int i = it * stride + (blockIdx.x * 256 + threadIdx.x) * 4;
        const float4 a = *(const float4*)(xb + i);
        const float4 c = *(const float4*)(xb + NPIX + i);
        const float4 d = *(const float4*)(xb + 2 * NPIX + i);
        const vint4 t4 = __builtin_nontemporal_load((const vint4*)(tb + i));
        float l;
        l = pix_loss(a.x, c.x, d.x, t4[0]); if (t4[0] > 0) { fs += l; fc++; } else bs += l;
        l = pix_loss(a.y, c.y, d.y, t4[1]); if (t4[1] > 0) { fs += l; fc++; } else bs += l;
        l = pix_loss(a.z, c.z, d.z, t4[2]); if (t4[2] > 0) { fs += l; fc++; } else bs += l;
        l = pix_loss(a.w, c.w, d.w, t4[3]); if (t4[3] > 0) { fs += l; fc++; } else bs += l;
    }
#pragma unroll
    for (int off = 32; off > 0; off >>= 1) {
        fs += __shfl_down(fs, off);
        bs += __shfl_down(bs, off);
        fc += __shfl_down(fc, off);
    }
    __shared__ float sfs[4], sbs[4];
    __shared__ int sfc[4];
    const int wid = threadIdx.x >> 6;
    if ((threadIdx.x & 63) == 0) { sfs[wid] = fs; sbs[wid] = bs; sfc[wid] = fc; }
    __syncthreads();
    if (threadIdx.x == 0) {
        const int slot = b * G1 + blockIdx.x;
        pfs[slot] = sfs[0] + sfs[1] + sfs[2] + sfs[3];
        pbs[slot] = sbs[0] + sbs[1] + sbs[2] + sbs[3];
        pfc[slot] = (unsigned)(sfc[0] + sfc[1] + sfc[2] + sfc[3]);
    }
}

// helper: reduce one image's partial arrays across the 256-thread block.
// Returns (via LDS broadcast) totals valid in ALL threads.
__device__ __forceinline__ void reduce_image(const float* __restrict__ pfs,
                                             const float* __restrict__ pbs,
                                             const unsigned* __restrict__ pfc,
                                             int b2, int tid,
                                             double* __restrict__ sda,
                                             double* __restrict__ sdb,
                                             unsigned* __restrict__ su,
                                             double& tfs, double& tbs, u64& tfc) {
    const float4 f4 = ((const float4*)pfs)[b2 * (G1 / 4) + tid];
    const float4 b4 = ((const float4*)pbs)[b2 * (G1 / 4) + tid];
    const uint4 c4 = ((const uint4*)pfc)[b2 * (G1 / 4) + tid];
    double fs = (double)f4.x + (double)f4.y + (double)f4.z + (double)f4.w;
    double bs = (double)b4.x + (double)b4.y + (double)b4.z + (double)b4.w;
    unsigned fc = c4.x + c4.y + c4.z + c4.w;
#pragma unroll
    for (int off = 32; off > 0; off >>= 1) {
        fs += __shfl_down(fs, off);
        bs += __shfl_down(bs, off);
        fc += __shfl_down(fc, off);
    }
    const int wid = tid >> 6;
    if ((tid & 63) == 0) { sda[wid] = fs; sdb[wid] = bs; su[wid] = fc; }
    __syncthreads();
    tfs = sda[0] + sda[1] + sda[2] + sda[3];
    tbs = sdb[0] + sdb[1] + sdb[2] + sdb[3];
    tfc = (u64)su[0] + su[1] + su[2] + su[3];
    __syncthreads();
}

// K2: merged tail. Every block decides its image's need independently from the
// (L2-hot) pfc partials; block (0,0) computes the final scalar when no image
// needs the top-k path (always, on this data). Hist path preserved for
// generality: LDS hist -> global merge -> done-counter -> fixup.
__global__ __launch_bounds__(256) void k_tail(const float* __restrict__ pfs,
                                              const float* __restrict__ pbs,
                                              const unsigned* __restrict__ pfc,
                                              const float* __restrict__ x,
                                              const int* __restrict__ tg,
                                              unsigned* __restrict__ hist_cnt,
                                              float* __restrict__ hist_sum,
                                              unsigned* __restrict__ flags,
                                              float* __restrict__ out,
                                              int have_hist) {
    const int b = blockIdx.y;
    const int tid = threadIdx.x;
    __shared__ double sda[4], sdb[4];
    __shared__ unsigned su[4];

    // own-image fg count (uniform)
    u64 fc_own;
    {
        const uint4 c4 = ((const uint4*)pfc)[b * (G1 / 4) + tid];
        unsigned s = c4.x + c4.y + c4.z + c4.w;
#pragma unroll
        for (int off = 32; off > 0; off >>= 1) s += __shfl_down(s, off);
        if ((tid & 63) == 0) su[tid >> 6] = s;
        __syncthreads();
        fc_own = (u64)su[0] + su[1] + su[2] + su[3];
        __syncthreads();
    }
    const u64 bg_own = (u64)NPIX - fc_own;
    const u64 mk_own = fc_own > MINK ? fc_own : MINK;
    const u64 k_own = bg_own < mk_own ? bg_own : mk_own;
    const bool need_own = (k_own < bg_own) && have_hist;

    // block (0,0): final scalar on the no-hist path
    if (blockIdx.x == 0 && b == 0) {
        double acc = 0.0;
        bool any_need = false;
        for (int b2 = 0; b2 < BATCH; ++b2) {
            double tfs, tbs; u64 tfc;
            reduce_image(pfs, pbs, pfc, b2, tid, sda, sdb, su, tfs, tbs, tfc);
            const u64 bg = (u64)NPIX - tfc;
            const u64 mk = tfc > MINK ? tfc : MINK;
            const u64 k = bg < mk ? bg : mk;
            if (k < bg && have_hist) any_need = true;
            const double fg_term = (tfc > 0) ? tfs / (double)tfc : 0.0;
            const u64 kd = k > 1 ? k : 1;
            const double bg_term = (bg > 0) ? tbs / (double)kd : 0.0;  // valid iff k>=bg (or !have_hist)
            acc += fg_term + bg_term;
        }
        if (tid == 0 && !any_need) out[0] = (float)(acc / (double)BATCH);
    }

    if (!need_own) return;

    // ---------------- hist path (not exercised on this data) ----------------
    __shared__ unsigned hc[NBINS];
    __shared__ float hs[NBINS];
    for (int i = tid; i < NBINS; i += 256) { hc[i] = 0u; hs[i] = 0.f; }
    __syncthreads();
    {
        const float* xb = x + (size_t)b * 3 * NPIX;
        const int* tb = tg + (size_t)b * NPIX;
        const int stride = HG * 256 * 4;
        for (int i = (blockIdx.x * 256 + tid) * 4; i < NPIX; i += stride) {
            const float4 a = *(const float4*)(xb + i);
            const float4 c = *(const float4*)(xb + NPIX + i);
            const float4 d = *(const float4*)(xb + 2 * NPIX + i);
            const int4 t4 = *(const int4*)(tb + i);
            float v[4][3] = {{a.x, c.x, d.x}, {a.y, c.y, d.y}, {a.z, c.z, d.z}, {a.w, c.w, d.w}};
            int tt[4] = {t4.x, t4.y, t4.z, t4.w};
#pragma unroll
            for (int j = 0; j < 4; ++j) {
                if (tt[j] == 0) {
                    float l = fmaxf(pix_loss(v[j][0], v[j][1], v[j][2], tt[j]), 0.f);
                    unsigned bin = __float_as_uint(l) >> 20;  // monotone for x>=0
                    atomicAdd(&hc[bin], 1u);
                    atomicAdd(&hs[bin], l);
                }
            }
        }
    }
    __syncthreads();
    for (int i = tid; i < NBINS; i += 256) {
        if (hc[i]) {
            atomicAdd(&hist_cnt[(size_t)b * NBINS + i], hc[i]);
            atomicAdd(&hist_sum[(size_t)b * NBINS + i], hs[i]);
        }
    }

    // participant count = HG * (#images needing hist); computed uniformly
    int nneed = 0;
    for (int b2 = 0; b2 < BATCH; ++b2) {
        const uint4 c4 = ((const uint4*)pfc)[b2 * (G1 / 4) + tid];
        unsigned s = c4.x + c4.y + c4.z + c4.w;
#pragma unroll
        for (int off = 32; off > 0; off >>= 1) s += __shfl_down(s, off);
        if ((tid & 63) == 0) su[tid >> 6] = s;
        __syncthreads();
        const u64 fc2 = (u64)su[0] + su[1] + su[2] + su[3];
        __syncthreads();
        const u64 bg2 = (u64)NPIX - fc2;
        const u64 mk2 = fc2 > MINK ? fc2 : MINK;
        const u64 k2 = bg2 < mk2 ? bg2 : mk2;
        if (k2 < bg2) nneed++;
    }

    __threadfence();
    __syncthreads();
    __shared__ int is_last;
    if (tid == 0) {
        unsigned v = atomicAdd(&flags[1], 1u);
        is_last = (v == (unsigned)(HG * nneed) - 1u) ? 1 : 0;
    }
    __syncthreads();
    if (!is_last) return;
    __threadfence();

    // fixup: recompute every image's terms; top-k from the global hist
    double acc = 0.0;
    for (int b2 = 0; b2 < BATCH; ++b2) {
        double tfs, tbs; u64 tfc;
        reduce_image(pfs, pbs, pfc, b2, tid, sda, sdb, su, tfs, tbs, tfc);
        const u64 bg = (u64)NPIX - tfc;
        const u64 mk = tfc > MINK ? tfc : MINK;
        const u64 k = bg < mk ? bg : mk;
        double bg_sel = tbs;
        if (k < bg) {
            for (int i = tid; i < NBINS; i += 256) {
                hc[i] = __hip_atomic_load(&hist_cnt[(size_t)b2 * NBINS + i],
                                          __ATOMIC_ACQUIRE, __HIP_MEMORY_SCOPE_AGENT);
                hs[i] = __hip_atomic_load(&hist_sum[(size_t)b2 * NBINS + i],
                                          __ATOMIC_ACQUIRE, __HIP_MEMORY_SCOPE_AGENT);
            }
            __syncthreads();
            if (tid == 0) {
                u64 cnt = 0; double s = 0.0, topk = 0.0;
                for (int i = NBINS - 1; i >= 0; --i) {
                    unsigned c = hc[i];
                    if (cnt + c >= k) {
                        double edge = (double)__uint_as_float(((unsigned)i) << 20);
                        topk = s + (double)(k - cnt) * edge;
                        break;
                    }
                    cnt += c;
                    s += (double)hs[i];
                }
                sda[0] = topk;
            }
            __syncthreads();
            bg_sel = sda[0];
            __syncthreads();
        }
        const double fg_term = (tfc > 0) ? tfs / (double)tfc : 0.0;
        const u64 kd = k > 1 ? k : 1;
        const double bg_term = (bg > 0) ? bg_sel / (double)kd : 0.0;
        acc += fg_term + bg_term;
    }
    if (tid == 0) out[0] = (float)(acc / (double)BATCH);
}

extern "C" void kernel_launch(void* const* d_in, const int* in_sizes, int n_in,
                              void* d_out, int out_size, void* d_ws, size_t ws_size,
                              hipStream_t stream) {
    const float* x = (const float*)d_in[0];
    const int* tg = (const int*)d_in[1];
    float* out = (float*)d_out;

    char* ws = (char*)d_ws;
    float* pfs = (float*)ws;                                   // 16 KB
    float* pbs = (float*)(ws + 16384);                         // 16 KB
    unsigned* pfc = (unsigned*)(ws + 32768);                   // 16 KB
    unsigned* flags = (unsigned*)(ws + 49152);                 // 128 B
    unsigned* hist_cnt = (unsigned*)(ws + 49280);              // 64 KB
    float* hist_sum = (float*)(ws + 49280 + (size_t)BATCH * NBINS * 4);  // 64 KB
    uint4* histz = (uint4*)(ws + 49280);                       // cnt+sum contiguous: 8192 uint4
    const size_t need_ws = 49280 + (size_t)BATCH * NBINS * 8;
    const int have_hist = (ws_size >= need_ws) ? 1 : 0;

    dim3 block(256);
    dim3 grid1(G1, BATCH);
    k_reduce<<<grid1, block, 0, stream>>>(x, tg, pfs, pbs, pfc, histz, flags, have_hist);
    dim3 grid2(HG, BATCH);
    k_tail<<<grid2, block, 0, stream>>>(pfs, pbs, pfc, x, tg,
                                        hist_cnt, hist_sum, flags, out, have_hist);
}

// Round 8
// 50.808 us; speedup vs baseline: 4.4538x; 1.0261x over previous
//
#include <hip/hip_runtime.h>

#define NPIX 4194304   // 64*256*256 per image
#define BATCH 4
#define MINK 1024ULL
#define NBINS 4096
#define G1 512         // blocks per image in k_reduce (2048 total = one full occupancy generation)
#define HG 256         // blocks per image in k_tail hist path

typedef unsigned long long u64;
typedef int vint4 __attribute__((ext_vector_type(4)));
typedef float vflt4 __attribute__((ext_vector_type(4)));

__device__ __forceinline__ float pix_loss(float v0, float v1, float v2, int t) {
    float m = fmaxf(fmaxf(v0, v1), v2);
    float lse = m + __logf(__expf(v0 - m) + __expf(v1 - m) + __expf(v2 - m));
    float xt = (t == 0) ? v0 : ((t == 1) ? v1 : v2);
    return lse - xt;
}

// K1: per-block partials via PLAIN STORES to unique slots — zero atomics.
// All streams non-temporal: zero reuse (caches flushed by harness between
// replays), so LLC/L2 allocation is pure overhead.
__global__ __launch_bounds__(256) void k_reduce(const float* __restrict__ x,
                                                const int* __restrict__ tg,
                                                float* __restrict__ pfs,
                                                float* __restrict__ pbs,
                                                unsigned* __restrict__ pfc,
                                                uint4* __restrict__ histz,
                                                unsigned* __restrict__ flags,
                                                int have_hist) {
    const int b = blockIdx.y;
    if (b == 0 && blockIdx.x < 32) {
        if (have_hist) histz[blockIdx.x * 256 + threadIdx.x] = make_uint4(0u, 0u, 0u, 0u);
        if (blockIdx.x == 0 && threadIdx.x == 0) flags[1] = 0u;
    }
    const float* xb = x + (size_t)b * 3 * NPIX;
    const int* tb = tg + (size_t)b * NPIX;
    float fs = 0.f, bs = 0.f;
    int fc = 0;
    const int stride = G1 * 256 * 4;  // pixels per grid sweep
#pragma unroll
    for (int it = 0; it < NPIX / stride; ++it) {
        const int i = it * stride + (blockIdx.x * 256 + threadIdx.x) * 4;
        const vflt4 a = __builtin_nontemporal_load((const vflt4*)(xb + i));
        const vflt4 c = __builtin_nontemporal_load((const vflt4*)(xb + NPIX + i));
        const vflt4 d = __builtin_nontemporal_load((const vflt4*)(xb + 2 * NPIX + i));
        const vint4 t4 = __builtin_nontemporal_load((const vint4*)(tb + i));
        float l;
        l = pix_loss(a[0], c[0], d[0], t4[0]); if (t4[0] > 0) { fs += l; fc++; } else bs += l;
        l = pix_loss(a[1], c[1], d[1], t4[1]); if (t4[1] > 0) { fs += l; fc++; } else bs += l;
        l = pix_loss(a[2], c[2], d[2], t4[2]); if (t4[2] > 0) { fs += l; fc++; } else bs += l;
        l = pix_loss(a[3], c[3], d[3], t4[3]); if (t4[3] > 0) { fs += l; fc++; } else bs += l;
    }
#pragma unroll
    for (int off = 32; off > 0; off >>= 1) {
        fs += __shfl_down(fs, off);
        bs += __shfl_down(bs, off);
        fc += __shfl_down(fc, off);
    }
    __shared__ float sfs[4], sbs[4];
    __shared__ int sfc[4];
    const int wid = threadIdx.x >> 6;
    if ((threadIdx.x & 63) == 0) { sfs[wid] = fs; sbs[wid] = bs; sfc[wid] = fc; }
    __syncthreads();
    if (threadIdx.x == 0) {
        const int slot = b * G1 + blockIdx.x;
        pfs[slot] = sfs[0] + sfs[1] + sfs[2] + sfs[3];
        pbs[slot] = sbs[0] + sbs[1] + sbs[2] + sbs[3];
        pfc[slot] = (unsigned)(sfc[0] + sfc[1] + sfc[2] + sfc[3]);
    }
}

// helper: reduce one image's partial arrays (G1 slots) across the block.
// Totals broadcast to ALL threads via LDS.
__device__ __forceinline__ void reduce_image(const float* __restrict__ pfs,
                                             const float* __restrict__ pbs,
                                             const unsigned* __restrict__ pfc,
                                             int b2, int tid,
                                             double* __restrict__ sda,
                                             double* __restrict__ sdb,
                                             unsigned* __restrict__ su,
                                             double& tfs, double& tbs, u64& tfc) {
    double fs = 0.0, bs = 0.0;
    unsigned fc = 0;
    if (tid < G1 / 4) {
        const float4 f4 = ((const float4*)pfs)[b2 * (G1 / 4) + tid];
        const float4 b4 = ((const float4*)pbs)[b2 * (G1 / 4) + tid];
        const uint4 c4 = ((const uint4*)pfc)[b2 * (G1 / 4) + tid];
        fs = (double)f4.x + (double)f4.y + (double)f4.z + (double)f4.w;
        bs = (double)b4.x + (double)b4.y + (double)b4.z + (double)b4.w;
        fc = c4.x + c4.y + c4.z + c4.w;
    }
#pragma unroll
    for (int off = 32; off > 0; off >>= 1) {
        fs += __shfl_down(fs, off);
        bs += __shfl_down(bs, off);
        fc += __shfl_down(fc, off);
    }
    const int wid = tid >> 6;
    if ((tid & 63) == 0) { sda[wid] = fs; sdb[wid] = bs; su[wid] = fc; }
    __syncthreads();
    tfs = sda[0] + sda[1] + sda[2] + sda[3];
    tbs = sdb[0] + sdb[1] + sdb[2] + sdb[3];
    tfc = (u64)su[0] + su[1] + su[2] + su[3];
    __syncthreads();
}

// K2: merged tail (structure proven in round 7). Fast path: block (0,0)
// computes the scalar; all other blocks exit after the own-image need check.
__global__ __launch_bounds__(256) void k_tail(const float* __restrict__ pfs,
                                              const float* __restrict__ pbs,
                                              const unsigned* __restrict__ pfc,
                                              const float* __restrict__ x,
                                              const int* __restrict__ tg,
                                              unsigned* __restrict__ hist_cnt,
                                              float* __restrict__ hist_sum,
                                              unsigned* __restrict__ flags,
                                              float* __restrict__ out,
                                              int have_hist) {
    const int b = blockIdx.y;
    const int tid = threadIdx.x;
    __shared__ double sda[4], sdb[4];
    __shared__ unsigned su[4];

    // own-image fg count (uniform across block)
    u64 fc_own;
    {
        unsigned s = 0;
        if (tid < G1 / 4) {
            const uint4 c4 = ((const uint4*)pfc)[b * (G1 / 4) + tid];
            s = c4.x + c4.y + c4.z + c4.w;
        }
#pragma unroll
        for (int off = 32; off > 0; off >>= 1) s += __shfl_down(s, off);
        if ((tid & 63) == 0) su[tid >> 6] = s;
        __syncthreads();
        fc_own = (u64)su[0] + su[1] + su[2] + su[3];
        __syncthreads();
    }
    const u64 bg_own = (u64)NPIX - fc_own;
    const u64 mk_own = fc_own > MINK ? fc_own : MINK;
    const u64 k_own = bg_own < mk_own ? bg_own : mk_own;
    const bool need_own = (k_own < bg_own) && have_hist;

    // block (0,0): final scalar on the no-hist path
    if (blockIdx.x == 0 && b == 0) {
        double acc = 0.0;
        bool any_need = false;
        for (int b2 = 0; b2 < BATCH; ++b2) {
            double tfs, tbs; u64 tfc;
            reduce_image(pfs, pbs, pfc, b2, tid, sda, sdb, su, tfs, tbs, tfc);
            const u64 bg = (u64)NPIX - tfc;
            const u64 mk = tfc > MINK ? tfc : MINK;
            const u64 k = bg < mk ? bg : mk;
            if (k < bg && have_hist) any_need = true;
            const double fg_term = (tfc > 0) ? tfs / (double)tfc : 0.0;
            const u64 kd = k > 1 ? k : 1;
            const double bg_term = (bg > 0) ? tbs / (double)kd : 0.0;  // valid iff k>=bg (or !have_hist)
            acc += fg_term + bg_term;
        }
        if (tid == 0 && !any_need) out[0] = (float)(acc / (double)BATCH);
    }

    if (!need_own) return;

    // ---------------- hist path (not exercised on this data) ----------------
    __shared__ unsigned hc[NBINS];
    __shared__ float hs[NBINS];
    for (int i = tid; i < NBINS; i += 256) { hc[i] = 0u; hs[i] = 0.f; }
    __syncthreads();
    {
        const float* xb = x + (size_t)b * 3 * NPIX;
        const int* tb = tg + (size_t)b * NPIX;
        const int stride = HG * 256 * 4;
        for (int i = (blockIdx.x * 256 + tid) * 4; i < NPIX; i += stride) {
            const float4 a = *(const float4*)(xb + i);
            const float4 c = *(const float4*)(xb + NPIX + i);
            const float4 d = *(const float4*)(xb + 2 * NPIX + i);
            const int4 t4 = *(const int4*)(tb + i);
            float v[4][3] = {{a.x, c.x, d.x}, {a.y, c.y, d.y}, {a.z, c.z, d.z}, {a.w, c.w, d.w}};
            int tt[4] = {t4.x, t4.y, t4.z, t4.w};
#pragma unroll
            for (int j = 0; j < 4; ++j) {
                if (tt[j] == 0) {
                    float l = fmaxf(pix_loss(v[j][0], v[j][1], v[j][2], tt[j]), 0.f);
                    unsigned bin = __float_as_uint(l) >> 20;  // monotone for x>=0
                    atomicAdd(&hc[bin], 1u);
                    atomicAdd(&hs[bin], l);
                }
            }
        }
    }
    __syncthreads();
    for (int i = tid; i < NBINS; i += 256) {
        if (hc[i]) {
            atomicAdd(&hist_cnt[(size_t)b * NBINS + i], hc[i]);
            atomicAdd(&hist_sum[(size_t)b * NBINS + i], hs[i]);
        }
    }

    // participant count = HG * (#images needing hist); computed uniformly
    int nneed = 0;
    for (int b2 = 0; b2 < BATCH; ++b2) {
        unsigned s = 0;
        if (tid < G1 / 4) {
            const uint4 c4 = ((const uint4*)pfc)[b2 * (G1 / 4) + tid];
            s = c4.x + c4.y + c4.z + c4.w;
        }
#pragma unroll
        for (int off = 32; off > 0; off >>= 1) s += __shfl_down(s, off);
        if ((tid & 63) == 0) su[tid >> 6] = s;
        __syncthreads();
        const u64 fc2 = (u64)su[0] + su[1] + su[2] + su[3];
        __syncthreads();
        const u64 bg2 = (u64)NPIX - fc2;
        const u64 mk2 = fc2 > MINK ? fc2 : MINK;
        const u64 k2 = bg2 < mk2 ? bg2 : mk2;
        if (k2 < bg2) nneed++;
    }

    __threadfence();
    __syncthreads();
    __shared__ int is_last;
    if (tid == 0) {
        unsigned v = atomicAdd(&flags[1], 1u);
        is_last = (v == (unsigned)(HG * nneed) - 1u) ? 1 : 0;
    }
    __syncthreads();
    if (!is_last) return;
    __threadfence();

    // fixup: recompute every image's terms; top-k from the global hist
    double acc = 0.0;
    for (int b2 = 0; b2 < BATCH; ++b2) {
        double tfs, tbs; u64 tfc;
        reduce_image(pfs, pbs, pfc, b2, tid, sda, sdb, su, tfs, tbs, tfc);
        const u64 bg = (u64)NPIX - tfc;
        const u64 mk = tfc > MINK ? tfc : MINK;
        const u64 k = bg < mk ? bg : mk;
        double bg_sel = tbs;
        if (k < bg) {
            for (int i = tid; i < NBINS; i += 256) {
                hc[i] = __hip_atomic_load(&hist_cnt[(size_t)b2 * NBINS + i],
                                          __ATOMIC_ACQUIRE, __HIP_MEMORY_SCOPE_AGENT);
                hs[i] = __hip_atomic_load(&hist_sum[(size_t)b2 * NBINS + i],
                                          __ATOMIC_ACQUIRE, __HIP_MEMORY_SCOPE_AGENT);
            }
            __syncthreads();
            if (tid == 0) {
                u64 cnt = 0; double s = 0.0, topk = 0.0;
                for (int i = NBINS - 1; i >= 0; --i) {
                    unsigned c = hc[i];
                    if (cnt + c >= k) {
                        double edge = (double)__uint_as_float(((unsigned)i) << 20);
                        topk = s + (double)(k - cnt) * edge;
                        break;
                    }
                    cnt += c;
                    s += (double)hs[i];
                }
                sda[0] = topk;
            }
            __syncthreads();
            bg_sel = sda[0];
            __syncthreads();
        }
        const double fg_term = (tfc > 0) ? tfs / (double)tfc : 0.0;
        const u64 kd = k > 1 ? k : 1;
        const double bg_term = (bg > 0) ? bg_sel / (double)kd : 0.0;
        acc += fg_term + bg_term;
    }
    if (tid == 0) out[0] = (float)(acc / (double)BATCH);
}

extern "C" void kernel_launch(void* const* d_in, const int* in_sizes, int n_in,
                              void* d_out, int out_size, void* d_ws, size_t ws_size,
                              hipStream_t stream) {
    const float* x = (const float*)d_in[0];
    const int* tg = (const int*)d_in[1];
    float* out = (float*)d_out;

    char* ws = (char*)d_ws;
    float* pfs = (float*)ws;                                   // 8 KB used
    float* pbs = (float*)(ws + 16384);                         // 8 KB used
    unsigned* pfc = (unsigned*)(ws + 32768);                   // 8 KB used
    unsigned* flags = (unsigned*)(ws + 49152);                 // 128 B
    unsigned* hist_cnt = (unsigned*)(ws + 49280);              // 64 KB
    float* hist_sum = (float*)(ws + 49280 + (size_t)BATCH * NBINS * 4);  // 64 KB
    uint4* histz = (uint4*)(ws + 49280);                       // cnt+sum contiguous: 8192 uint4
    const size_t need_ws = 49280 + (size_t)BATCH * NBINS * 8;
    const int have_hist = (ws_size >= need_ws) ? 1 : 0;

    dim3 block(256);
    dim3 grid1(G1, BATCH);
    k_reduce<<<grid1, block, 0, stream>>>(x, tg, pfs, pbs, pfc, histz, flags, have_hist);
    dim3 grid2(HG, BATCH);
    k_tail<<<grid2, block, 0, stream>>>(pfs, pbs, pfc, x, tg,
                                        hist_cnt, hist_sum, flags, out, have_hist);
}